// Round 2
// baseline (457.826 us; speedup 1.0000x reference)
//
#include <hip/hip_runtime.h>
#include <math.h>

#define B 16
#define D 8
#define FDIM 2
#define N 512
#define E 10          // D + FDIM
#define NPAIR (D*D)
#define GJW (2*E)     // augmented width for Gauss-Jordan

// ---- workspace layout (float offsets) ----
#define OFF_SIGMA 0            // B*E*E            = 1600
#define OFF_NU    1600         // B*N*E            = 81920
#define OFF_AINV  83520        // B*D*E*E          = 12800
#define OFF_LDA   96320        // B*D              = 128
#define OFF_Q     96448        // B*D*N            = 65536
#define OFF_LOGK  161984       // B*D*N            = 65536
#define OFF_MUD   227520       // B*D              = 128
#define OFF_V     227648       // B*D*E            = 1280
#define OFF_S     228928       // NPAIR*B*E*E      = 102400
#define OFF_LDR   331328       // NPAIR*B          = 1024
#define OFF_CA    332352       // NPAIR*B*N        = 524288
#define OFF_CB    856640       // NPAIR*B*N        = 524288
#define OFF_EDD   1380928      // B*D*D            = 1024
#define OFF_TR    1381952      // B*D              = 128
// total = 1382080 floats = 5.53 MB

// ---------------------------------------------------------------------------
// K1: assemble Sigma (B,E,E) and nu (B,N,E)
__global__ __launch_bounds__(256) void k_build(
    const float* __restrict__ obs_mean, const float* __restrict__ obs_var,
    const float* __restrict__ action_mean, const float* __restrict__ action_var,
    const float* __restrict__ cross_cov, const float* __restrict__ X,
    float* __restrict__ ws) {
  int b = blockIdx.x;
  float* Sigma = ws + OFF_SIGMA + b * E * E;
  float* nu = ws + OFF_NU + (size_t)b * N * E;
  for (int idx = threadIdx.x; idx < E * E; idx += blockDim.x) {
    int e = idx / E, f = idx % E;
    float v;
    if (e < D && f < D)      v = obs_var[(b * D + e) * D + f];
    else if (e < D)          v = cross_cov[(b * D + e) * FDIM + (f - D)];
    else if (f < D)          v = cross_cov[(b * D + f) * FDIM + (e - D)];
    else                     v = action_var[(b * FDIM + (e - D)) * FDIM + (f - D)];
    Sigma[idx] = v;
  }
  for (int idx = threadIdx.x; idx < N * E; idx += blockDim.x) {
    int n = idx / E, e = idx % E;
    float mu = (e < D) ? obs_mean[b * D + e] : action_mean[b * FDIM + (e - D)];
    nu[idx] = X[n * E + e] - mu;
  }
}

// ---------------------------------------------------------------------------
// Cooperative Gauss-Jordan with partial pivoting on an augmented E x GJW
// system held in LDS. One wave (64 threads) per matrix. Left half must be the
// square matrix; on exit right half holds the solution, *logdet gets
// log|det(left)|. Single-wave lockstep makes the swap-step load/store safe.
// ---------------------------------------------------------------------------

// K2: Ainv per (b,d) + logdetA
__global__ __launch_bounds__(64) void k_ainv(const float* __restrict__ ell,
                                             float* __restrict__ ws) {
  int bd = blockIdx.x;
  int b = bd / D, d = bd % D;
  __shared__ float M[E][GJW];
  __shared__ float pivrow[GJW];
  __shared__ float colfac[E];
  __shared__ int s_piv;
  __shared__ float s_logdet;
  const float* Sigma = ws + OFF_SIGMA + b * E * E;
  int tid = threadIdx.x;
  for (int idx = tid; idx < E * GJW; idx += 64) {
    int r = idx / GJW, c = idx % GJW;
    float v;
    if (c < E) {
      v = Sigma[r * E + c];
      if (r == c) { float l = ell[d * E + r]; v += l * l; }
    } else {
      v = (c - E == r) ? 1.0f : 0.0f;
    }
    M[r][c] = v;
  }
  if (tid == 0) s_logdet = 0.0f;
  __syncthreads();
  for (int k = 0; k < E; k++) {
    if (tid == 0) {
      int pr = k; float best = fabsf(M[k][k]);
      for (int r = k + 1; r < E; r++) {
        float v = fabsf(M[r][k]);
        if (v > best) { best = v; pr = r; }
      }
      s_piv = pr;
      s_logdet += logf(fabsf(M[pr][k]));
    }
    __syncthreads();
    int pr = s_piv;
    float piv = M[pr][k];           // load before any store (single wave)
    if (tid < GJW) {
      int c = tid;
      float tmp = M[pr][c];
      float tk = M[k][c];
      float pw = tmp / piv;
      pivrow[c] = pw;
      M[pr][c] = tk;
      M[k][c] = pw;
    }
    __syncthreads();
    if (tid < E) colfac[tid] = M[tid][k];
    __syncthreads();
    for (int idx = tid; idx < E * GJW; idx += 64) {
      int r = idx / GJW, c = idx % GJW;
      if (r != k) M[r][c] -= colfac[r] * pivrow[c];
    }
    __syncthreads();
  }
  float* Ainv = ws + OFF_AINV + (b * D + d) * E * E;
  for (int idx = tid; idx < E * E; idx += 64) {
    int r = idx / E, c = idx % E;
    Ainv[idx] = M[r][E + c];
  }
  if (tid == 0) ws[OFF_LDA + b * D + d] = s_logdet;
}

// K3: S = solve(R, Sigma) per (a<=d, b) + logdetR
__global__ __launch_bounds__(64) void k_S(const float* __restrict__ ell,
                                          float* __restrict__ ws) {
  int blk = blockIdx.x;
  int p = blk / B, b = blk % B;
  int a = p / D, d = p % D;
  if (a > d) return;
  __shared__ float M[E][GJW];
  __shared__ float pivrow[GJW];
  __shared__ float colfac[E];
  __shared__ int s_piv;
  __shared__ float s_logdet;
  const float* Sigma = ws + OFF_SIGMA + b * E * E;
  int tid = threadIdx.x;
  for (int idx = tid; idx < E * GJW; idx += 64) {
    int r = idx / GJW, c = idx % GJW;
    float v;
    if (c < E) {
      float la = ell[a * E + c], ld = ell[d * E + c];
      float iLs = 1.0f / (la * la) + 1.0f / (ld * ld);
      v = Sigma[r * E + c] * iLs + ((r == c) ? 1.0f : 0.0f);
    } else {
      v = Sigma[r * E + (c - E)];
    }
    M[r][c] = v;
  }
  if (tid == 0) s_logdet = 0.0f;
  __syncthreads();
  for (int k = 0; k < E; k++) {
    if (tid == 0) {
      int pr = k; float best = fabsf(M[k][k]);
      for (int r = k + 1; r < E; r++) {
        float v = fabsf(M[r][k]);
        if (v > best) { best = v; pr = r; }
      }
      s_piv = pr;
      s_logdet += logf(fabsf(M[pr][k]));
    }
    __syncthreads();
    int pr = s_piv;
    float piv = M[pr][k];
    if (tid < GJW) {
      int c = tid;
      float tmp = M[pr][c];
      float tk = M[k][c];
      float pw = tmp / piv;
      pivrow[c] = pw;
      M[pr][c] = tk;
      M[k][c] = pw;
    }
    __syncthreads();
    if (tid < E) colfac[tid] = M[tid][k];
    __syncthreads();
    for (int idx = tid; idx < E * GJW; idx += 64) {
      int r = idx / GJW, c = idx % GJW;
      if (r != k) M[r][c] -= colfac[r] * pivrow[c];
    }
    __syncthreads();
  }
  float* S = ws + OFF_S + ((size_t)p * B + b) * E * E;
  for (int idx = tid; idx < E * E; idx += 64) {
    int r = idx / E, c = idx % E;
    S[idx] = M[r][E + c];
  }
  if (tid == 0) ws[OFF_LDR + p * B + b] = s_logdet;
}

// ---------------------------------------------------------------------------
// K4: per (b,d): quad, q, logk, mu_delta, w -> V
__global__ __launch_bounds__(256) void k_qk(const float* __restrict__ ell,
                                            const float* __restrict__ alpha_sq,
                                            const float* __restrict__ beta,
                                            float* __restrict__ ws) {
  int bd = blockIdx.x;
  int b = bd / D, d = bd % D;
  __shared__ float sAinv[E * E];
  __shared__ float siLam[E];
  __shared__ float red[256];
  __shared__ float wsh[E];
  int tid = threadIdx.x;
  const float* nu = ws + OFF_NU + (size_t)b * N * E;
  const float* Ainv = ws + OFF_AINV + (b * D + d) * E * E;
  float* qv = ws + OFF_Q + (size_t)(b * D + d) * N;
  float* lk = ws + OFF_LOGK + (size_t)(b * D + d) * N;
  for (int i = tid; i < E * E; i += 256) sAinv[i] = Ainv[i];
  if (tid < E) { float l = ell[d * E + tid]; siLam[tid] = 1.0f / (l * l); }
  __syncthreads();
  float logdetLam = 0.0f;
#pragma unroll
  for (int e = 0; e < E; e++) { float l = ell[d * E + e]; logdetLam += logf(l * l); }
  float a2 = alpha_sq[d];
  float lda = ws[OFF_LDA + b * D + d];
  float c0 = 0.5f * (logdetLam - lda);
  float lga = logf(a2);
  float acc_mu = 0.0f;
  float acc_w[E];
#pragma unroll
  for (int e = 0; e < E; e++) acc_w[e] = 0.0f;
  for (int n = tid; n < N; n += 256) {
    float x[E];
#pragma unroll
    for (int e = 0; e < E; e++) x[e] = nu[n * E + e];
    float quad = 0.0f;
#pragma unroll
    for (int e = 0; e < E; e++) {
      float t = 0.0f;
#pragma unroll
      for (int f = 0; f < E; f++) t += sAinv[e * E + f] * x[f];
      quad += x[e] * t;
    }
    float qval = a2 * __expf(c0 - 0.5f * quad);
    qv[n] = qval;
    float s2 = 0.0f;
#pragma unroll
    for (int e = 0; e < E; e++) s2 += x[e] * x[e] * siLam[e];
    lk[n] = lga - 0.5f * s2;
    float bq = beta[d * N + n] * qval;
    acc_mu += bq;
#pragma unroll
    for (int e = 0; e < E; e++) acc_w[e] += bq * x[e];
  }
  // block reductions: mu_delta then w[0..E)
  red[tid] = acc_mu; __syncthreads();
  for (int s = 128; s > 0; s >>= 1) { if (tid < s) red[tid] += red[tid + s]; __syncthreads(); }
  if (tid == 0) ws[OFF_MUD + b * D + d] = red[0];
  __syncthreads();
#pragma unroll
  for (int e = 0; e < E; e++) {
    red[tid] = acc_w[e]; __syncthreads();
    for (int s = 128; s > 0; s >>= 1) { if (tid < s) red[tid] += red[tid + s]; __syncthreads(); }
    if (tid == 0) wsh[e] = red[0];
    __syncthreads();
  }
  if (tid == 0) {
    const float* Sigma = ws + OFF_SIGMA + b * E * E;
    float u[E];
#pragma unroll
    for (int f = 0; f < E; f++) {
      float s = 0.0f;
#pragma unroll
      for (int g = 0; g < E; g++) s += sAinv[f * E + g] * wsh[g];
      u[f] = s;
    }
#pragma unroll
    for (int e = 0; e < E; e++) {
      float s = 0.0f;
#pragma unroll
      for (int f = 0; f < E; f++) s += Sigma[e * E + f] * u[f];
      ws[OFF_V + (b * D + d) * E + e] = s;
    }
  }
}

// ---------------------------------------------------------------------------
// K5: c_a, c_b per (a<=d, b, n)
__global__ __launch_bounds__(256) void k_cab(const float* __restrict__ ell,
                                             float* __restrict__ ws) {
  int blk = blockIdx.x;
  int p = blk / B, b = blk % B;
  int a = p / D, d = p % D;
  if (a > d) return;
  __shared__ float sS[E * E];
  __shared__ float iLa[E], iLd[E];
  int tid = threadIdx.x;
  const float* S = ws + OFF_S + ((size_t)p * B + b) * E * E;
  for (int i = tid; i < E * E; i += 256) sS[i] = S[i];
  if (tid < E) {
    float la = ell[a * E + tid]; iLa[tid] = 1.0f / (la * la);
    float ld = ell[d * E + tid]; iLd[tid] = 1.0f / (ld * ld);
  }
  __syncthreads();
  const float* nu = ws + OFF_NU + (size_t)b * N * E;
  const float* lka = ws + OFF_LOGK + (size_t)(b * D + a) * N;
  const float* lkd = ws + OFF_LOGK + (size_t)(b * D + d) * N;
  float* ca = ws + OFF_CA + ((size_t)p * B + b) * N;
  float* cb = ws + OFF_CB + ((size_t)p * B + b) * N;
  for (int n = tid; n < N; n += 256) {
    float pa[E], pd[E];
#pragma unroll
    for (int e = 0; e < E; e++) {
      float x = nu[n * E + e];
      pa[e] = x * iLa[e];
      pd[e] = x * iLd[e];
    }
    float da = 0.0f, db = 0.0f;
#pragma unroll
    for (int e = 0; e < E; e++) {
      float ta = 0.0f, td = 0.0f;
#pragma unroll
      for (int f = 0; f < E; f++) {
        float s = sS[e * E + f];
        ta += s * pa[f];
        td += s * pd[f];
      }
      da += pa[e] * ta;
      db += pd[e] * td;
    }
    ca[n] = lka[n] + 0.5f * da;
    cb[n] = lkd[n] + 0.5f * db;
  }
}

// ---------------------------------------------------------------------------
// K6 (dominant): Q contraction per (a<=d, b)
__global__ __launch_bounds__(256) void k_q(const float* __restrict__ ell,
                                           const float* __restrict__ beta,
                                           const float* __restrict__ invK,
                                           float* __restrict__ ws) {
  int blk = blockIdx.x;
  int p = blk / B, b = blk % B;
  int a = p / D, d = p % D;
  if (a > d) return;
  __shared__ float t[N * E];     // t[i][f] = nu_i^T W  (20 KB)
  __shared__ float sW[E * E];
  __shared__ float sca[N];
  __shared__ float sba[N];
  __shared__ float red[256];
  int tid = threadIdx.x;
  float ldr = ws[OFF_LDR + p * B + b];
  if (tid < E * E) {
    int e = tid / E, f = tid % E;
    float la = ell[a * E + e], ld = ell[d * E + f];
    float S = ws[OFF_S + ((size_t)p * B + b) * E * E + tid];
    sW[tid] = S / (la * la) / (ld * ld);
  }
  const float* ca = ws + OFF_CA + ((size_t)p * B + b) * N;
  const float* cb = ws + OFF_CB + ((size_t)p * B + b) * N;
  for (int i = tid; i < N; i += 256) {
    sca[i] = ca[i] - 0.5f * ldr;
    sba[i] = beta[a * N + i];
  }
  __syncthreads();
  const float* nu = ws + OFF_NU + (size_t)b * N * E;
  float xj[2][E], cbj[2], bdj[2];
#pragma unroll
  for (int s = 0; s < 2; s++) {
    int j = tid + s * 256;
#pragma unroll
    for (int e = 0; e < E; e++) xj[s][e] = nu[j * E + e];
    cbj[s] = cb[j];
    bdj[s] = beta[d * N + j];
#pragma unroll
    for (int f = 0; f < E; f++) {
      float acc = 0.0f;
#pragma unroll
      for (int e = 0; e < E; e++) acc += xj[s][e] * sW[e * E + f];
      t[j * E + f] = acc;
    }
  }
  __syncthreads();
  float acc_rows = 0.0f, acc_tr = 0.0f;
  const float* invKa = invK + (size_t)a * N * N;
  bool diag = (a == d);
  for (int i = 0; i < N; i++) {
    float ti[E];
#pragma unroll
    for (int f = 0; f < E; f++) ti[f] = t[i * E + f];
    float cai = sca[i];
    float bai = sba[i];
#pragma unroll
    for (int s = 0; s < 2; s++) {
      int j = tid + s * 256;
      float m = 0.0f;
#pragma unroll
      for (int f = 0; f < E; f++) m += ti[f] * xj[s][f];
      float Qv = __expf(cai + m + cbj[s]);
      acc_rows += (bai * bdj[s]) * Qv;
      if (diag) acc_tr += invKa[(size_t)i * N + j] * Qv;
    }
  }
  red[tid] = acc_rows; __syncthreads();
  for (int s = 128; s > 0; s >>= 1) { if (tid < s) red[tid] += red[tid + s]; __syncthreads(); }
  if (tid == 0) {
    float v = red[0];
    ws[OFF_EDD + b * D * D + a * D + d] = v;
    ws[OFF_EDD + b * D * D + d * D + a] = v;
  }
  if (diag) {
    __syncthreads();
    red[tid] = acc_tr; __syncthreads();
    for (int s = 128; s > 0; s >>= 1) { if (tid < s) red[tid] += red[tid + s]; __syncthreads(); }
    if (tid == 0) ws[OFF_TR + b * D + a] = red[0];
  }
}

// ---------------------------------------------------------------------------
// K7: final assembly
__global__ __launch_bounds__(64) void k_final(
    const float* __restrict__ obs_mean, const float* __restrict__ obs_var,
    const float* __restrict__ alpha_sq, const float* __restrict__ sigma_sq_eps,
    const float* __restrict__ ws, float* __restrict__ out) {
  int b = blockIdx.x;
  int tid = threadIdx.x;
  const float* mud = ws + OFF_MUD + b * D;
  if (tid < D) out[b * D + tid] = obs_mean[b * D + tid] + mud[tid];
  if (tid < D * D) {
    int i = tid / D, j = tid % D;
    float sd = ws[OFF_EDD + b * D * D + tid] - mud[i] * mud[j];
    if (i == j) sd += alpha_sq[i] - ws[OFF_TR + b * D + i] + sigma_sq_eps[i];
    const float* V = ws + OFF_V;
    float cxd = V[(b * D + j) * E + i];   // C_xd[b,i,j] = V[b,j,i]
    float cdx = V[(b * D + i) * E + j];   // C_xd[b,j,i] = V[b,i,j]
    out[B * D + b * D * D + tid] = obs_var[b * D * D + tid] + sd + cxd + cdx;
  }
}

// ---------------------------------------------------------------------------
extern "C" void kernel_launch(void* const* d_in, const int* in_sizes, int n_in,
                              void* d_out, int out_size, void* d_ws, size_t ws_size,
                              hipStream_t stream) {
  const float* obs_mean     = (const float*)d_in[0];
  const float* obs_var      = (const float*)d_in[1];
  const float* action_mean  = (const float*)d_in[2];
  const float* action_var   = (const float*)d_in[3];
  const float* cross_cov    = (const float*)d_in[4];
  const float* X_train      = (const float*)d_in[5];
  const float* ell          = (const float*)d_in[6];
  const float* alpha_sq     = (const float*)d_in[7];
  const float* sigma_sq_eps = (const float*)d_in[8];
  const float* beta         = (const float*)d_in[9];
  const float* inv_K        = (const float*)d_in[10];
  float* out = (float*)d_out;
  float* ws = (float*)d_ws;

  k_build<<<B, 256, 0, stream>>>(obs_mean, obs_var, action_mean, action_var,
                                 cross_cov, X_train, ws);
  k_ainv<<<B * D, 64, 0, stream>>>(ell, ws);
  k_S<<<NPAIR * B, 64, 0, stream>>>(ell, ws);
  k_qk<<<B * D, 256, 0, stream>>>(ell, alpha_sq, beta, ws);
  k_cab<<<NPAIR * B, 256, 0, stream>>>(ell, ws);
  k_q<<<NPAIR * B, 256, 0, stream>>>(ell, beta, inv_K, ws);
  k_final<<<B, 64, 0, stream>>>(obs_mean, obs_var, alpha_sq, sigma_sq_eps, ws, out);
}

// Round 3
// 226.130 us; speedup vs baseline: 2.0246x; 2.0246x over previous
//
#include <hip/hip_runtime.h>
#include <math.h>

#define B 16
#define D 8
#define FDIM 2
#define N 512
#define E 10          // D + FDIM
#define NPAIR (D*D)
#define NP36 36       // pairs a<=d
#define GJW (2*E)     // augmented width for Gauss-Jordan
#define NT 4          // i-tiles per (pair,b) in k_q
#define TIL 128       // i-tile size
#define TSTR 12       // padded t-row stride (floats, 16B-aligned rows)

// ---- workspace layout (float offsets) ----
#define OFF_SIGMA 0            // B*E*E            = 1600
#define OFF_NU    1600         // B*N*E            = 81920
#define OFF_AINV  83520        // B*D*E*E          = 12800
#define OFF_LDA   96320        // B*D              = 128
#define OFF_LOGK  96448        // B*D*N            = 65536
#define OFF_MUD   161984       // B*D              = 128
#define OFF_V     162112       // B*D*E            = 1280
#define OFF_S     163392       // NPAIR*B*E*E      = 102400
#define OFF_LDR   265792       // NPAIR*B          = 1024
#define OFF_CA    266816       // NPAIR*B*N        = 524288
#define OFF_CB    791104       // NPAIR*B*N        = 524288
#define OFF_EDDP  1315392      // NP36*B*NT        = 2304
#define OFF_TRP   1317696      // D*B*NT           = 512
// total = 1318208 floats = 5.27 MB

__device__ __forceinline__ void decode_pair(int p36, int* pa, int* pd) {
  int a = 0, rem = p36;
  while (rem >= D - a) { rem -= (D - a); a++; }
  *pa = a; *pd = a + rem;
}

// ---------------------------------------------------------------------------
// K1: assemble Sigma (B,E,E) and nu (B,N,E)
__global__ __launch_bounds__(256) void k_build(
    const float* __restrict__ obs_mean, const float* __restrict__ obs_var,
    const float* __restrict__ action_mean, const float* __restrict__ action_var,
    const float* __restrict__ cross_cov, const float* __restrict__ X,
    float* __restrict__ ws) {
  int b = blockIdx.x;
  float* Sigma = ws + OFF_SIGMA + b * E * E;
  float* nu = ws + OFF_NU + (size_t)b * N * E;
  for (int idx = threadIdx.x; idx < E * E; idx += blockDim.x) {
    int e = idx / E, f = idx % E;
    float v;
    if (e < D && f < D)      v = obs_var[(b * D + e) * D + f];
    else if (e < D)          v = cross_cov[(b * D + e) * FDIM + (f - D)];
    else if (f < D)          v = cross_cov[(b * D + f) * FDIM + (e - D)];
    else                     v = action_var[(b * FDIM + (e - D)) * FDIM + (f - D)];
    Sigma[idx] = v;
  }
  for (int idx = threadIdx.x; idx < N * E; idx += blockDim.x) {
    int n = idx / E, e = idx % E;
    float mu = (e < D) ? obs_mean[b * D + e] : action_mean[b * FDIM + (e - D)];
    nu[idx] = X[n * E + e] - mu;
  }
}

// ---------------------------------------------------------------------------
// K2: Ainv per (b,d) + logdetA (cooperative Gauss-Jordan, 1 wave)
__global__ __launch_bounds__(64) void k_ainv(const float* __restrict__ ell,
                                             float* __restrict__ ws) {
  int bd = blockIdx.x;
  int b = bd / D, d = bd % D;
  __shared__ float M[E][GJW];
  __shared__ float pivrow[GJW];
  __shared__ float colfac[E];
  __shared__ int s_piv;
  __shared__ float s_logdet;
  const float* Sigma = ws + OFF_SIGMA + b * E * E;
  int tid = threadIdx.x;
  for (int idx = tid; idx < E * GJW; idx += 64) {
    int r = idx / GJW, c = idx % GJW;
    float v;
    if (c < E) {
      v = Sigma[r * E + c];
      if (r == c) { float l = ell[d * E + r]; v += l * l; }
    } else {
      v = (c - E == r) ? 1.0f : 0.0f;
    }
    M[r][c] = v;
  }
  if (tid == 0) s_logdet = 0.0f;
  __syncthreads();
  for (int k = 0; k < E; k++) {
    if (tid == 0) {
      int pr = k; float best = fabsf(M[k][k]);
      for (int r = k + 1; r < E; r++) {
        float v = fabsf(M[r][k]);
        if (v > best) { best = v; pr = r; }
      }
      s_piv = pr;
      s_logdet += logf(fabsf(M[pr][k]));
    }
    __syncthreads();
    int pr = s_piv;
    float piv = M[pr][k];           // load before any store (single wave)
    if (tid < GJW) {
      int c = tid;
      float tmp = M[pr][c];
      float tk = M[k][c];
      float pw = tmp / piv;
      pivrow[c] = pw;
      M[pr][c] = tk;
      M[k][c] = pw;
    }
    __syncthreads();
    if (tid < E) colfac[tid] = M[tid][k];
    __syncthreads();
    for (int idx = tid; idx < E * GJW; idx += 64) {
      int r = idx / GJW, c = idx % GJW;
      if (r != k) M[r][c] -= colfac[r] * pivrow[c];
    }
    __syncthreads();
  }
  float* Ainv = ws + OFF_AINV + (b * D + d) * E * E;
  for (int idx = tid; idx < E * E; idx += 64) {
    int r = idx / E, c = idx % E;
    Ainv[idx] = M[r][E + c];
  }
  if (tid == 0) ws[OFF_LDA + b * D + d] = s_logdet;
}

// K3: S = solve(R, Sigma) per (a<=d, b) + logdetR
__global__ __launch_bounds__(64) void k_S(const float* __restrict__ ell,
                                          float* __restrict__ ws) {
  int blk = blockIdx.x;       // NP36 * B
  int p36 = blk / B, b = blk % B;
  int a, d;
  decode_pair(p36, &a, &d);
  int p = a * D + d;
  __shared__ float M[E][GJW];
  __shared__ float pivrow[GJW];
  __shared__ float colfac[E];
  __shared__ int s_piv;
  __shared__ float s_logdet;
  const float* Sigma = ws + OFF_SIGMA + b * E * E;
  int tid = threadIdx.x;
  for (int idx = tid; idx < E * GJW; idx += 64) {
    int r = idx / GJW, c = idx % GJW;
    float v;
    if (c < E) {
      float la = ell[a * E + c], ld = ell[d * E + c];
      float iLs = 1.0f / (la * la) + 1.0f / (ld * ld);
      v = Sigma[r * E + c] * iLs + ((r == c) ? 1.0f : 0.0f);
    } else {
      v = Sigma[r * E + (c - E)];
    }
    M[r][c] = v;
  }
  if (tid == 0) s_logdet = 0.0f;
  __syncthreads();
  for (int k = 0; k < E; k++) {
    if (tid == 0) {
      int pr = k; float best = fabsf(M[k][k]);
      for (int r = k + 1; r < E; r++) {
        float v = fabsf(M[r][k]);
        if (v > best) { best = v; pr = r; }
      }
      s_piv = pr;
      s_logdet += logf(fabsf(M[pr][k]));
    }
    __syncthreads();
    int pr = s_piv;
    float piv = M[pr][k];
    if (tid < GJW) {
      int c = tid;
      float tmp = M[pr][c];
      float tk = M[k][c];
      float pw = tmp / piv;
      pivrow[c] = pw;
      M[pr][c] = tk;
      M[k][c] = pw;
    }
    __syncthreads();
    if (tid < E) colfac[tid] = M[tid][k];
    __syncthreads();
    for (int idx = tid; idx < E * GJW; idx += 64) {
      int r = idx / GJW, c = idx % GJW;
      if (r != k) M[r][c] -= colfac[r] * pivrow[c];
    }
    __syncthreads();
  }
  float* S = ws + OFF_S + ((size_t)p * B + b) * E * E;
  for (int idx = tid; idx < E * E; idx += 64) {
    int r = idx / E, c = idx % E;
    S[idx] = M[r][E + c];
  }
  if (tid == 0) ws[OFF_LDR + p * B + b] = s_logdet;
}

// ---------------------------------------------------------------------------
// K4: per (b,d): quad, q, logk, mu_delta, w -> V
__global__ __launch_bounds__(256) void k_qk(const float* __restrict__ ell,
                                            const float* __restrict__ alpha_sq,
                                            const float* __restrict__ beta,
                                            float* __restrict__ ws) {
  int bd = blockIdx.x;
  int b = bd / D, d = bd % D;
  __shared__ float sAinv[E * E];
  __shared__ float siLam[E];
  __shared__ float red[256];
  __shared__ float wsh[E];
  int tid = threadIdx.x;
  const float* nu = ws + OFF_NU + (size_t)b * N * E;
  const float* Ainv = ws + OFF_AINV + (b * D + d) * E * E;
  float* lk = ws + OFF_LOGK + (size_t)(b * D + d) * N;
  for (int i = tid; i < E * E; i += 256) sAinv[i] = Ainv[i];
  if (tid < E) { float l = ell[d * E + tid]; siLam[tid] = 1.0f / (l * l); }
  __syncthreads();
  float logdetLam = 0.0f;
#pragma unroll
  for (int e = 0; e < E; e++) { float l = ell[d * E + e]; logdetLam += logf(l * l); }
  float a2 = alpha_sq[d];
  float lda = ws[OFF_LDA + b * D + d];
  float c0 = 0.5f * (logdetLam - lda);
  float lga = logf(a2);
  float acc_mu = 0.0f;
  float acc_w[E];
#pragma unroll
  for (int e = 0; e < E; e++) acc_w[e] = 0.0f;
  for (int n = tid; n < N; n += 256) {
    float x[E];
#pragma unroll
    for (int e = 0; e < E; e++) x[e] = nu[n * E + e];
    float quad = 0.0f;
#pragma unroll
    for (int e = 0; e < E; e++) {
      float t = 0.0f;
#pragma unroll
      for (int f = 0; f < E; f++) t += sAinv[e * E + f] * x[f];
      quad += x[e] * t;
    }
    float qval = a2 * __expf(c0 - 0.5f * quad);
    float s2 = 0.0f;
#pragma unroll
    for (int e = 0; e < E; e++) s2 += x[e] * x[e] * siLam[e];
    lk[n] = lga - 0.5f * s2;
    float bq = beta[d * N + n] * qval;
    acc_mu += bq;
#pragma unroll
    for (int e = 0; e < E; e++) acc_w[e] += bq * x[e];
  }
  red[tid] = acc_mu; __syncthreads();
  for (int s = 128; s > 0; s >>= 1) { if (tid < s) red[tid] += red[tid + s]; __syncthreads(); }
  if (tid == 0) ws[OFF_MUD + b * D + d] = red[0];
  __syncthreads();
#pragma unroll
  for (int e = 0; e < E; e++) {
    red[tid] = acc_w[e]; __syncthreads();
    for (int s = 128; s > 0; s >>= 1) { if (tid < s) red[tid] += red[tid + s]; __syncthreads(); }
    if (tid == 0) wsh[e] = red[0];
    __syncthreads();
  }
  if (tid == 0) {
    const float* Sigma = ws + OFF_SIGMA + b * E * E;
    float u[E];
#pragma unroll
    for (int f = 0; f < E; f++) {
      float s = 0.0f;
#pragma unroll
      for (int g = 0; g < E; g++) s += sAinv[f * E + g] * wsh[g];
      u[f] = s;
    }
#pragma unroll
    for (int e = 0; e < E; e++) {
      float s = 0.0f;
#pragma unroll
      for (int f = 0; f < E; f++) s += Sigma[e * E + f] * u[f];
      ws[OFF_V + (b * D + d) * E + e] = s;
    }
  }
}

// ---------------------------------------------------------------------------
// K5: c_a, c_b per (a<=d, b, n)
__global__ __launch_bounds__(256) void k_cab(const float* __restrict__ ell,
                                             float* __restrict__ ws) {
  int blk = blockIdx.x;       // NP36 * B
  int p36 = blk / B, b = blk % B;
  int a, d;
  decode_pair(p36, &a, &d);
  int p = a * D + d;
  __shared__ float sS[E * E];
  __shared__ float iLa[E], iLd[E];
  int tid = threadIdx.x;
  const float* S = ws + OFF_S + ((size_t)p * B + b) * E * E;
  for (int i = tid; i < E * E; i += 256) sS[i] = S[i];
  if (tid < E) {
    float la = ell[a * E + tid]; iLa[tid] = 1.0f / (la * la);
    float ld = ell[d * E + tid]; iLd[tid] = 1.0f / (ld * ld);
  }
  __syncthreads();
  const float* nu = ws + OFF_NU + (size_t)b * N * E;
  const float* lka = ws + OFF_LOGK + (size_t)(b * D + a) * N;
  const float* lkd = ws + OFF_LOGK + (size_t)(b * D + d) * N;
  float* ca = ws + OFF_CA + ((size_t)p * B + b) * N;
  float* cb = ws + OFF_CB + ((size_t)p * B + b) * N;
  for (int n = tid; n < N; n += 256) {
    float pa[E], pd[E];
#pragma unroll
    for (int e = 0; e < E; e++) {
      float x = nu[n * E + e];
      pa[e] = x * iLa[e];
      pd[e] = x * iLd[e];
    }
    float da = 0.0f, db = 0.0f;
#pragma unroll
    for (int e = 0; e < E; e++) {
      float ta = 0.0f, td = 0.0f;
#pragma unroll
      for (int f = 0; f < E; f++) {
        float s = sS[e * E + f];
        ta += s * pa[f];
        td += s * pd[f];
      }
      da += pa[e] * ta;
      db += pd[e] * td;
    }
    ca[n] = lka[n] + 0.5f * da;
    cb[n] = lkd[n] + 0.5f * db;
  }
}

// ---------------------------------------------------------------------------
// K6 (dominant): Q contraction. Grid: NP36*B*NT blocks, 256 threads.
// Block covers i-tile of TIL=128 (split 2 ihalves x 64) x all 512 j.
// Thread: Jt=4 consecutive j in registers, It=2 i-rows per step.
__global__ __launch_bounds__(256, 4) void k_q(const float* __restrict__ ell,
                                              const float* __restrict__ beta,
                                              const float* __restrict__ invK,
                                              float* __restrict__ ws) {
  int bx = blockIdx.x;
  int tile = bx & (NT - 1);
  int rest = bx >> 2;          // NT == 4
  int b = rest & (B - 1);
  int p36 = rest >> 4;         // B == 16
  int a, d;
  decode_pair(p36, &a, &d);
  int p = a * D + d;
  bool diag = (a == d);
  int i0 = tile * TIL;

  __shared__ float t[TIL * TSTR];     // 6144 B (row-padded for float4 reads)
  __shared__ float snu[TIL * E];      // 5120 B
  __shared__ float sW[E * E];
  __shared__ float sca[TIL];
  __shared__ float sba[TIL];
  __shared__ float red[256];

  int tid = threadIdx.x;
  const float* nu = ws + OFF_NU + (size_t)b * N * E;
  float ldr = ws[OFF_LDR + p * B + b];

  // stage sW = diag(iLa) * S * diag(iLd)
  if (tid < E * E) {
    int e = tid / E, f = tid % E;
    float la = ell[a * E + e], ld = ell[d * E + f];
    float S = ws[OFF_S + ((size_t)p * B + b) * E * E + tid];
    sW[tid] = S / (la * la) / (ld * ld);
  }
  // stage nu i-tile (coalesced), ca/beta_a tiles
  for (int idx = tid; idx < TIL * E; idx += 256) snu[idx] = nu[i0 * E + idx];
  const float* ca = ws + OFF_CA + ((size_t)p * B + b) * N;
  for (int il = tid; il < TIL; il += 256) {
    sca[il] = ca[i0 + il] - 0.5f * ldr;
    sba[il] = beta[a * N + i0 + il];
  }

  // per-thread j fragment: 4 consecutive j (coalesced float4 global loads)
  int jgrp = tid & 127;
  int ihalf = tid >> 7;
  int jbase = jgrp * 4;
  float xr[40];
  {
    const float4* nup = (const float4*)(nu + (size_t)jbase * E);
#pragma unroll
    for (int q4 = 0; q4 < 10; q4++) {
      float4 v = nup[q4];
      xr[q4 * 4 + 0] = v.x; xr[q4 * 4 + 1] = v.y;
      xr[q4 * 4 + 2] = v.z; xr[q4 * 4 + 3] = v.w;
    }
  }
  const float* cb = ws + OFF_CB + ((size_t)p * B + b) * N;
  float cbv[4], vb[4];
#pragma unroll
  for (int k = 0; k < 4; k++) {
    cbv[k] = cb[jbase + k];
    vb[k] = beta[d * N + jbase + k];
  }
  __syncthreads();

  // t[i][f] = sum_e snu[i][e] * sW[e][f]
  for (int idx = tid; idx < TIL * E; idx += 256) {
    int il = idx / E, f = idx % E;
    float acc = 0.0f;
#pragma unroll
    for (int e = 0; e < E; e++) acc += snu[il * E + e] * sW[e * E + f];
    t[il * TSTR + f] = acc;
  }
  __syncthreads();

  const float* invKa = invK + (size_t)a * N * N;
  float acc_rows = 0.0f, acc_tr = 0.0f;
  int ibase = ihalf * 64;
#pragma unroll 2
  for (int ii = 0; ii < 32; ii++) {
    int il = ibase + ii * 2;
    const float4* tp = (const float4*)&t[il * TSTR];
    float4 t0a = tp[0], t0b = tp[1], t0c = tp[2];     // row il: f0..9 (+2 pad)
    float4 t1a = tp[3], t1b = tp[4], t1c = tp[5];     // row il+1
    float tr0[10] = {t0a.x, t0a.y, t0a.z, t0a.w, t0b.x, t0b.y, t0b.z, t0b.w, t0c.x, t0c.y};
    float tr1[10] = {t1a.x, t1a.y, t1a.z, t1a.w, t1b.x, t1b.y, t1b.z, t1b.w, t1c.x, t1c.y};
    float cai0 = sca[il], cai1 = sca[il + 1];
    float ba0 = sba[il], ba1 = sba[il + 1];
    float4 r0, r1;
    if (diag) {
      r0 = *(const float4*)(invKa + (size_t)(i0 + il) * N + jbase);
      r1 = *(const float4*)(invKa + (size_t)(i0 + il + 1) * N + jbase);
    }
#pragma unroll
    for (int k = 0; k < 4; k++) {
      float m0 = 0.0f, m1 = 0.0f;
#pragma unroll
      for (int f = 0; f < E; f++) {
        float x = xr[k * 10 + f];
        m0 += tr0[f] * x;
        m1 += tr1[f] * x;
      }
      float q0 = __expf(cai0 + cbv[k] + m0);
      float q1 = __expf(cai1 + cbv[k] + m1);
      acc_rows += vb[k] * (ba0 * q0 + ba1 * q1);
      if (diag) {
        const float* kr0 = (const float*)&r0;
        const float* kr1 = (const float*)&r1;
        acc_tr += kr0[k] * q0 + kr1[k] * q1;
      }
    }
  }

  red[tid] = acc_rows; __syncthreads();
  for (int s = 128; s > 0; s >>= 1) { if (tid < s) red[tid] += red[tid + s]; __syncthreads(); }
  if (tid == 0) ws[OFF_EDDP + (p36 * B + b) * NT + tile] = red[0];
  if (diag) {
    __syncthreads();
    red[tid] = acc_tr; __syncthreads();
    for (int s = 128; s > 0; s >>= 1) { if (tid < s) red[tid] += red[tid + s]; __syncthreads(); }
    if (tid == 0) ws[OFF_TRP + (a * B + b) * NT + tile] = red[0];
  }
}

// ---------------------------------------------------------------------------
// K7: final assembly (sums k_q tile partials)
__global__ __launch_bounds__(64) void k_final(
    const float* __restrict__ obs_mean, const float* __restrict__ obs_var,
    const float* __restrict__ alpha_sq, const float* __restrict__ sigma_sq_eps,
    const float* __restrict__ ws, float* __restrict__ out) {
  int b = blockIdx.x;
  int tid = threadIdx.x;
  const float* mud = ws + OFF_MUD + b * D;
  if (tid < D) out[b * D + tid] = obs_mean[b * D + tid] + mud[tid];
  if (tid < D * D) {
    int i = tid / D, j = tid % D;
    int a = i < j ? i : j;
    int dd = i < j ? j : i;
    int p36 = a * D - a * (a - 1) / 2 + (dd - a);
    float edd = 0.0f;
#pragma unroll
    for (int tt = 0; tt < NT; tt++) edd += ws[OFF_EDDP + (p36 * B + b) * NT + tt];
    float sd = edd - mud[i] * mud[j];
    if (i == j) {
      float tr = 0.0f;
#pragma unroll
      for (int tt = 0; tt < NT; tt++) tr += ws[OFF_TRP + (i * B + b) * NT + tt];
      sd += alpha_sq[i] - tr + sigma_sq_eps[i];
    }
    const float* V = ws + OFF_V;
    float cxd = V[(b * D + j) * E + i];   // C_xd[b,i,j] = V[b,j,i]
    float cdx = V[(b * D + i) * E + j];   // C_xd[b,j,i] = V[b,i,j]
    out[B * D + b * D * D + tid] = obs_var[b * D * D + tid] + sd + cxd + cdx;
  }
}

// ---------------------------------------------------------------------------
extern "C" void kernel_launch(void* const* d_in, const int* in_sizes, int n_in,
                              void* d_out, int out_size, void* d_ws, size_t ws_size,
                              hipStream_t stream) {
  const float* obs_mean     = (const float*)d_in[0];
  const float* obs_var      = (const float*)d_in[1];
  const float* action_mean  = (const float*)d_in[2];
  const float* action_var   = (const float*)d_in[3];
  const float* cross_cov    = (const float*)d_in[4];
  const float* X_train      = (const float*)d_in[5];
  const float* ell          = (const float*)d_in[6];
  const float* alpha_sq     = (const float*)d_in[7];
  const float* sigma_sq_eps = (const float*)d_in[8];
  const float* beta         = (const float*)d_in[9];
  const float* inv_K        = (const float*)d_in[10];
  float* out = (float*)d_out;
  float* ws = (float*)d_ws;

  k_build<<<B, 256, 0, stream>>>(obs_mean, obs_var, action_mean, action_var,
                                 cross_cov, X_train, ws);
  k_ainv<<<B * D, 64, 0, stream>>>(ell, ws);
  k_S<<<NP36 * B, 64, 0, stream>>>(ell, ws);
  k_qk<<<B * D, 256, 0, stream>>>(ell, alpha_sq, beta, ws);
  k_cab<<<NP36 * B, 256, 0, stream>>>(ell, ws);
  k_q<<<NP36 * B * NT, 256, 0, stream>>>(ell, beta, inv_K, ws);
  k_final<<<B, 64, 0, stream>>>(obs_mean, obs_var, alpha_sq, sigma_sq_eps, ws, out);
}